// Round 9
// baseline (535.197 us; speedup 1.0000x reference)
//
#include <hip/hip_runtime.h>
#include <hip/hip_bf16.h>

#define N_TOK 8192
#define IN_F  2048
#define OUT_F 8192
#define NB    16
#define BS    512
#define BM    128
#define MAX_MT 272          // worst-case padded M-tiles

typedef short          bf16x8  __attribute__((ext_vector_type(8)));
typedef unsigned short ushort8 __attribute__((ext_vector_type(8)));
typedef float          f32x4   __attribute__((ext_vector_type(4)));
typedef _Float16       f16x8   __attribute__((ext_vector_type(8)));

// ws layout (~235 MB, proven in R4-R7)
#define WS_COUNTS 0
#define WS_TSTART 64
#define WS_SEL    256                           // 8192 u16
#define WS_INV    (32*1024)                     // 8192*4 u32
#define WS_LISTS  (192*1024)                    // 16*8192 int
#define WS_XBF    (1ull<<20)                    // x_bf 32MB (w2_bf aliases after fc1)
#define WS_W1BF   (WS_XBF + 33554432ull)        // w1_bf 32MB
#define WS_W2BF   WS_XBF
#define WS_H      (WS_XBF + 67108864ull)        // h: 272*128*512*2 = 34MB
#define WS_YP     (WS_H + 35651584ull)          // yp: 272*128*2048*2 = 136MB fp16

static __device__ __forceinline__ unsigned short f2bf(float f) {
    __hip_bfloat16 h = __float2bfloat16(f);
    return *reinterpret_cast<unsigned short*>(&h);
}

static __device__ __forceinline__ void gload16(const unsigned short* g, unsigned short* lds) {
    __builtin_amdgcn_global_load_lds(
        (const __attribute__((address_space(1))) unsigned int*)g,
        (__attribute__((address_space(3))) unsigned int*)lds, 16, 0, 0);
}

// ---------------- router: fp64-accurate logits, top-4, pack selection ----------------
__global__ __launch_bounds__(256) void router_kernel(
    const float* __restrict__ x, const float* __restrict__ Wr,
    const float* __restrict__ br, unsigned short* __restrict__ sel)
{
    const int tid = threadIdx.x;
    const int lt = tid & 63;
    const int wv = tid >> 6;
    const int tok = blockIdx.x * 4 + wv;
    const int e = lt >> 2, p = lt & 3;
    const float4* xp = (const float4*)(x + (size_t)tok * IN_F);
    const float4* wp = (const float4*)(Wr + (size_t)e * IN_F);
    double s = 0.0;
    for (int j = p; j < IN_F / 4; j += 4) {
        float4 a = xp[j], w = wp[j];
        s += (double)a.x * w.x + (double)a.y * w.y + (double)a.z * w.z + (double)a.w * w.w;
    }
    s += __shfl_down(s, 2);
    s += __shfl_down(s, 1);
    __shared__ double logits[4][NB];
    if (p == 0) logits[wv][e] = s + (double)br[e];
    __syncthreads();
    if (lt == 0) {
        unsigned used = 0, packed = 0;
        #pragma unroll
        for (int kk = 0; kk < 4; ++kk) {
            int best = 0; double bv = -1.0e300;
            #pragma unroll
            for (int i = 0; i < NB; ++i)
                if (!((used >> i) & 1u) && logits[wv][i] > bv) { bv = logits[wv][i]; best = i; }
            used |= 1u << best;
            packed |= (unsigned)best << (4 * kk);
        }
        sel[tok] = (unsigned short)packed;
    }
}

// ---------------- build per-expert token lists + inverse map (deterministic) ----------------
__global__ __launch_bounds__(256) void build_lists_kernel(
    const unsigned short* __restrict__ sel, int* __restrict__ counts,
    int* __restrict__ lists, unsigned* __restrict__ inv)
{
    const int e = blockIdx.x;
    const int t = threadIdx.x;
    unsigned short mysel[N_TOK / 256];
    int cnt = 0;
    #pragma unroll
    for (int i = 0; i < N_TOK / 256; ++i) {
        unsigned s = sel[i * 256 + t];
        mysel[i] = (unsigned short)s;
        bool m = ((s & 15u) == (unsigned)e) | (((s >> 4) & 15u) == (unsigned)e) |
                 (((s >> 8) & 15u) == (unsigned)e) | (((s >> 12) & 15u) == (unsigned)e);
        cnt += m ? 1 : 0;
    }
    __shared__ int ps[256];
    ps[t] = cnt;
    __syncthreads();
    #pragma unroll
    for (int off = 1; off < 256; off <<= 1) {
        int v = (t >= off) ? ps[t - off] : 0;
        __syncthreads();
        ps[t] += v;
        __syncthreads();
    }
    int pos = ps[t] - cnt;
    if (t == 255) counts[e] = ps[255];
    #pragma unroll
    for (int i = 0; i < N_TOK / 256; ++i) {
        unsigned s = mysel[i];
        bool m = ((s & 15u) == (unsigned)e) | (((s >> 4) & 15u) == (unsigned)e) |
                 (((s >> 8) & 15u) == (unsigned)e) | (((s >> 12) & 15u) == (unsigned)e);
        if (m) {
            const int tok = i * 256 + t;
            int j = ((s & 15u) == (unsigned)e) ? 0 :
                    (((s >> 4) & 15u) == (unsigned)e) ? 1 :
                    (((s >> 8) & 15u) == (unsigned)e) ? 2 : 3;
            inv[tok * 4 + j] = ((unsigned)e << 16) | (unsigned)pos;
            lists[e * N_TOK + pos++] = tok;
        }
    }
}

__global__ void scan_kernel(const int* __restrict__ counts, int* __restrict__ tstart)
{
    if (threadIdx.x == 0) {
        int acc = 0;
        for (int i = 0; i < NB; ++i) { tstart[i] = acc; acc += (counts[i] + BM - 1) / BM; }
        tstart[NB] = acc;
    }
}

// ---------------- fp32 -> bf16 convert; optional per-row XOR-swizzle of 16B k-slots ----------------
__global__ __launch_bounds__(256) void convert_kernel(
    const float* __restrict__ src, unsigned short* __restrict__ dst, int sh, int swz)
{
    const int total = 1 << 21;
    for (int id = blockIdx.x * 256 + threadIdx.x; id < total; id += 2048 * 256) {
        const int row = id >> sh;
        const int sr  = id & ((1 << sh) - 1);
        const int ps  = swz ? (sr ^ (row & 7)) : sr;
        const float4* s4 = (const float4*)(src + ((size_t)id << 3));
        float4 p0 = s4[0], p1 = s4[1];
        ushort8 o;
        o[0] = f2bf(p0.x); o[1] = f2bf(p0.y); o[2] = f2bf(p0.z); o[3] = f2bf(p0.w);
        o[4] = f2bf(p1.x); o[5] = f2bf(p1.y); o[6] = f2bf(p1.z); o[7] = f2bf(p1.w);
        *(ushort8*)(dst + (((size_t)(row) << sh) << 3) + ((size_t)ps << 3)) = o;
    }
}

#define LDA(dst, ke) \
    { _Pragma("unroll") for (int i = 0; i < 4; ++i) { \
        dst##0[i] = *(const bf16x8*)(aP[i] + (ke)); \
        dst##1[i] = *(const bf16x8*)(aP[i] + (ke) + 32); } }

#define STB(ke, buf) \
    { _Pragma("unroll") for (int g = 0; g < 4; ++g) \
        gload16(bS[g] + (ke), &Bs[buf][(wave << 11) + (g << 9)]); }

#define COMP(buf, ar) \
    { _Pragma("unroll") for (int hf = 0; hf < 2; ++hf) { \
        bf16x8 b0 = *(const bf16x8*)&Bs[buf][offB[0] ^ (hf << 5)]; \
        bf16x8 b1 = *(const bf16x8*)&Bs[buf][offB[1] ^ (hf << 5)]; \
        bf16x8 b2 = *(const bf16x8*)&Bs[buf][offB[2] ^ (hf << 5)]; \
        bf16x8 b3 = *(const bf16x8*)&Bs[buf][offB[3] ^ (hf << 5)]; \
        bf16x8* av = hf ? ar##1 : ar##0; \
        _Pragma("unroll") for (int i = 0; i < 4; ++i) { \
            acc[i][0] = __builtin_amdgcn_mfma_f32_16x16x32_bf16(av[i], b0, acc[i][0], 0, 0, 0); \
            acc[i][1] = __builtin_amdgcn_mfma_f32_16x16x32_bf16(av[i], b1, acc[i][1], 0, 0, 0); \
            acc[i][2] = __builtin_amdgcn_mfma_f32_16x16x32_bf16(av[i], b2, acc[i][2], 0, 0, 0); \
            acc[i][3] = __builtin_amdgcn_mfma_f32_16x16x32_bf16(av[i], b3, acc[i][3], 0, 0, 0); } } }

// ======== fc1: A (gathered x) direct-to-registers, B (W1) via 2x16KB LDS ========
__global__ __launch_bounds__(256) void fc1_kernel(
    const unsigned short* __restrict__ x_bf, const unsigned short* __restrict__ w1_bf,
    const int* __restrict__ lists, const int* __restrict__ counts,
    const int* __restrict__ tstart, unsigned short* __restrict__ h)
{
    __shared__ unsigned short Bs[2][BM * 64];
    const int bid = blockIdx.x;
    const int newid = (bid & 7) * 136 + (bid >> 3);   // bijective: 1088 = 8*136
    const int nt = newid & 3, mt = newid >> 2;
    if (mt >= tstart[NB]) return;
    int b = 0;
    #pragma unroll
    for (int i = 1; i < NB; ++i) b += (mt >= tstart[i]);
    const int cnt  = counts[b];
    const int row0 = (mt - tstart[b]) * BM;
    const int tid  = threadIdx.x;
    const int wave = tid >> 6, lane = tid & 63;
    const int lr16 = lane & 15, q = lane >> 4;
    const int wm = (wave >> 1) * 64, wn = (wave & 1) * 64;

    // A: per-lane fragment pointers (gathered rows, linear x_bf)
    const unsigned short* aP[4];
    #pragma unroll
    for (int i = 0; i < 4; ++i) {
        const int gr = min(row0 + wm + i * 16 + lr16, cnt - 1);
        aP[i] = x_bf + (size_t)lists[b * N_TOK + gr] * IN_F + q * 8;
    }
    // B staging sources (pre-swizzled w1_bf, read linearly)
    const unsigned short* bS[4];
    #pragma unroll
    for (int g = 0; g < 4; ++g) {
        const int rg = wave * 32 + g * 8 + (lane >> 3);
        bS[g] = w1_bf + (size_t)(b * BS + nt * BM + rg) * IN_F + (lane & 7) * 8;
    }
    int offB[4];
    #pragma unroll
    for (int j = 0; j < 4; ++j) {
        const int r = wn + j * 16 + lr16;
        offB[j] = r * 64 + ((q ^ (r & 7)) << 3);
    }

    f32x4 acc[4][4];
    #pragma unroll
    for (int i = 0; i < 4; ++i)
        #pragma unroll
        for (int j = 0; j < 4; ++j) acc[i][j] = (f32x4)0.0f;

    bf16x8 aE0[4], aE1[4], aO0[4], aO1[4];
    STB(0, 0); LDA(aE, 0);

    const int NK = IN_F / 64;   // 32 (even)
    for (int k = 0; k < NK; k += 2) {
        __syncthreads();                        // B(k) in Bs[0], aE loaded
        if (k + 1 < NK) { STB((k + 1) * 64, 1); LDA(aO, (k + 1) * 64); }
        COMP(0, aE)
        __syncthreads();                        // B(k+1) in Bs[1], aO loaded
        if (k + 2 < NK) { STB((k + 2) * 64, 0); LDA(aE, (k + 2) * 64); }
        COMP(1, aO)
    }
    // epilogue: exact gelu, linear h store
    #pragma unroll
    for (int i = 0; i < 4; ++i) {
        #pragma unroll
        for (int r = 0; r < 4; ++r) {
            const int lrow = wm + i * 16 + q * 4 + r;
            if (row0 + lrow < cnt) {
                const size_t hrow = (size_t)(mt * BM + lrow) * BS;
                #pragma unroll
                for (int j = 0; j < 4; ++j) {
                    float v = acc[i][j][r];
                    v = 0.5f * v * (1.0f + erff(v * 0.70710678118654752f));
                    h[hrow + nt * BM + wn + j * 16 + lr16] = f2bf(v);
                }
            }
        }
    }
}

// ======== fc2: A (h) direct-to-registers, B (W2) via 2x16KB LDS -> yp fp16 ========
__global__ __launch_bounds__(256) void fc2_kernel(
    const unsigned short* __restrict__ h, const unsigned short* __restrict__ w2_bf,
    const int* __restrict__ counts, const int* __restrict__ tstart,
    _Float16* __restrict__ yp)
{
    __shared__ unsigned short Bs[2][BM * 64];
    const int bid = blockIdx.x;
    const int newid = (bid & 7) * 544 + (bid >> 3);   // bijective: 4352 = 8*544
    const int nt = newid & 15, mt = newid >> 4;
    if (mt >= tstart[NB]) return;
    int b = 0;
    #pragma unroll
    for (int i = 1; i < NB; ++i) b += (mt >= tstart[i]);
    const int cnt  = counts[b];
    const int row0 = (mt - tstart[b]) * BM;
    const int tid  = threadIdx.x;
    const int wave = tid >> 6, lane = tid & 63;
    const int lr16 = lane & 15, q = lane >> 4;
    const int wm = (wave >> 1) * 64, wn = (wave & 1) * 64;

    const unsigned short* aP[4];
    #pragma unroll
    for (int i = 0; i < 4; ++i)
        aP[i] = h + (size_t)(mt * BM + wm + i * 16 + lr16) * BS + q * 8;
    const unsigned short* bS[4];
    #pragma unroll
    for (int g = 0; g < 4; ++g) {
        const int rg = wave * 32 + g * 8 + (lane >> 3);
        bS[g] = w2_bf + (size_t)(nt * BM + rg) * OUT_F + b * BS + (lane & 7) * 8;
    }
    int offB[4];
    #pragma unroll
    for (int j = 0; j < 4; ++j) {
        const int r = wn + j * 16 + lr16;
        offB[j] = r * 64 + ((q ^ (r & 7)) << 3);
    }

    f32x4 acc[4][4];
    #pragma unroll
    for (int i = 0; i < 4; ++i)
        #pragma unroll
        for (int j = 0; j < 4; ++j) acc[i][j] = (f32x4)0.0f;

    bf16x8 aE0[4], aE1[4], aO0[4], aO1[4];
    STB(0, 0); LDA(aE, 0);

    const int NK = BS / 64;   // 8 (even)
    for (int k = 0; k < NK; k += 2) {
        __syncthreads();
        if (k + 1 < NK) { STB((k + 1) * 64, 1); LDA(aO, (k + 1) * 64); }
        COMP(0, aE)
        __syncthreads();
        if (k + 2 < NK) { STB((k + 2) * 64, 0); LDA(aE, (k + 2) * 64); }
        COMP(1, aO)
    }
    // epilogue: store fp16 partials in list order
    #pragma unroll
    for (int i = 0; i < 4; ++i) {
        #pragma unroll
        for (int r = 0; r < 4; ++r) {
            const int lrow = wm + i * 16 + q * 4 + r;
            if (row0 + lrow < cnt) {
                _Float16* yrow = yp + (size_t)(mt * BM + lrow) * IN_F + nt * BM + wn + lr16;
                #pragma unroll
                for (int j = 0; j < 4; ++j)
                    yrow[j * 16] = (_Float16)acc[i][j][r];
            }
        }
    }
}

// ---------------- reduce: y[t] = sum of the token's 4 fp16 partial rows ----------------
__global__ __launch_bounds__(256) void reduce_kernel(
    const _Float16* __restrict__ yp, const unsigned* __restrict__ inv,
    const int* __restrict__ tstart, float* __restrict__ y)
{
    const int tok = blockIdx.x;
    __shared__ size_t rbase[4];
    if (threadIdx.x < 4) {
        unsigned v = inv[tok * 4 + threadIdx.x];
        rbase[threadIdx.x] = (size_t)(tstart[v >> 16] * BM + (int)(v & 0xFFFFu)) * IN_F;
    }
    __syncthreads();
    const int c = threadIdx.x * 8;
    f16x8 v0 = *(const f16x8*)(yp + rbase[0] + c);
    f16x8 v1 = *(const f16x8*)(yp + rbase[1] + c);
    f16x8 v2 = *(const f16x8*)(yp + rbase[2] + c);
    f16x8 v3 = *(const f16x8*)(yp + rbase[3] + c);
    float out[8];
    #pragma unroll
    for (int j = 0; j < 8; ++j)
        out[j] = (float)v0[j] + (float)v1[j] + (float)v2[j] + (float)v3[j];
    float4* yo = (float4*)(y + (size_t)tok * IN_F + c);
    yo[0] = make_float4(out[0], out[1], out[2], out[3]);
    yo[1] = make_float4(out[4], out[5], out[6], out[7]);
}

extern "C" void kernel_launch(void* const* d_in, const int* in_sizes, int n_in,
                              void* d_out, int out_size, void* d_ws, size_t ws_size,
                              hipStream_t stream) {
    const float* x  = (const float*)d_in[0];
    const float* Wr = (const float*)d_in[1];
    const float* br = (const float*)d_in[2];
    const float* W1 = (const float*)d_in[3];
    const float* W2 = (const float*)d_in[4];
    float* y = (float*)d_out;
    char* ws = (char*)d_ws;
    int* counts = (int*)(ws + WS_COUNTS);
    int* tstart = (int*)(ws + WS_TSTART);
    unsigned short* sel = (unsigned short*)(ws + WS_SEL);
    unsigned* inv = (unsigned*)(ws + WS_INV);
    int* lists  = (int*)(ws + WS_LISTS);
    unsigned short* x_bf  = (unsigned short*)(ws + WS_XBF);
    unsigned short* w1_bf = (unsigned short*)(ws + WS_W1BF);
    unsigned short* w2_bf = (unsigned short*)(ws + WS_W2BF);
    unsigned short* h     = (unsigned short*)(ws + WS_H);
    _Float16* yp          = (_Float16*)(ws + WS_YP);

    hipLaunchKernelGGL(router_kernel, dim3(N_TOK / 4), dim3(256), 0, stream, x, Wr, br, sel);
    hipLaunchKernelGGL(build_lists_kernel, dim3(NB), dim3(256), 0, stream, sel, counts, lists, inv);
    hipLaunchKernelGGL(scan_kernel, dim3(1), dim3(64), 0, stream, counts, tstart);
    hipLaunchKernelGGL(convert_kernel, dim3(2048), dim3(256), 0, stream, x,  x_bf,  8, 0);
    hipLaunchKernelGGL(convert_kernel, dim3(2048), dim3(256), 0, stream, W1, w1_bf, 8, 1);
    hipLaunchKernelGGL(fc1_kernel, dim3(4 * MAX_MT), dim3(256), 0, stream, x_bf, w1_bf, lists, counts, tstart, h);
    hipLaunchKernelGGL(convert_kernel, dim3(2048), dim3(256), 0, stream, W2, w2_bf, 10, 1);
    hipLaunchKernelGGL(fc2_kernel, dim3(16 * MAX_MT), dim3(256), 0, stream, h, w2_bf, counts, tstart, yp);
    hipLaunchKernelGGL(reduce_kernel, dim3(N_TOK), dim3(256), 0, stream, yp, inv, tstart, y);
}

// Round 10
// 505.514 us; speedup vs baseline: 1.0587x; 1.0587x over previous
//
#include <hip/hip_runtime.h>
#include <hip/hip_bf16.h>

#define N_TOK 8192
#define IN_F  2048
#define OUT_F 8192
#define NB    16
#define BS    512
#define BM    128
#define MAX_MT 272          // worst-case padded M-tiles

typedef short          bf16x8  __attribute__((ext_vector_type(8)));
typedef unsigned short ushort8 __attribute__((ext_vector_type(8)));
typedef float          f32x4   __attribute__((ext_vector_type(4)));
typedef _Float16       f16x8   __attribute__((ext_vector_type(8)));

// ws layout (peak ~203 MB)
#define WS_COUNTS 0
#define WS_TSTART 64
#define WS_SEL    256                           // 8192 u16
#define WS_INV    (32*1024)                     // 8192*4 u32
#define WS_LISTS  (192*1024)                    // 16*8192 int
#define WS_XG     (1ull<<20)                    // xg: 34816*2048*2 = 136MB (list-ordered, swizzled)
#define WS_YP     WS_XG                         // yp aliases xg (dead after fc1)
#define WS_H      (WS_XG + 142606336ull)        // h: 34816*512*2 = 34MB
#define WS_W1BF   (WS_H + 35651584ull)          // w1_bf 32MB
#define WS_W2BF   WS_W1BF                       // w2_bf aliases w1_bf (dead after fc1)

static __device__ __forceinline__ unsigned short f2bf(float f) {
    __hip_bfloat16 h = __float2bfloat16(f);
    return *reinterpret_cast<unsigned short*>(&h);
}

static __device__ __forceinline__ void gload16(const unsigned short* g, unsigned short* lds) {
    __builtin_amdgcn_global_load_lds(
        (const __attribute__((address_space(1))) unsigned int*)g,
        (__attribute__((address_space(3))) unsigned int*)lds, 16, 0, 0);
}

#define MFMA16(ai, bi) \
    acc[0][0] = __builtin_amdgcn_mfma_f32_16x16x32_bf16(ai##0, bi##0, acc[0][0], 0, 0, 0); \
    acc[0][1] = __builtin_amdgcn_mfma_f32_16x16x32_bf16(ai##0, bi##1, acc[0][1], 0, 0, 0); \
    acc[0][2] = __builtin_amdgcn_mfma_f32_16x16x32_bf16(ai##0, bi##2, acc[0][2], 0, 0, 0); \
    acc[0][3] = __builtin_amdgcn_mfma_f32_16x16x32_bf16(ai##0, bi##3, acc[0][3], 0, 0, 0); \
    acc[1][0] = __builtin_amdgcn_mfma_f32_16x16x32_bf16(ai##1, bi##0, acc[1][0], 0, 0, 0); \
    acc[1][1] = __builtin_amdgcn_mfma_f32_16x16x32_bf16(ai##1, bi##1, acc[1][1], 0, 0, 0); \
    acc[1][2] = __builtin_amdgcn_mfma_f32_16x16x32_bf16(ai##1, bi##2, acc[1][2], 0, 0, 0); \
    acc[1][3] = __builtin_amdgcn_mfma_f32_16x16x32_bf16(ai##1, bi##3, acc[1][3], 0, 0, 0); \
    acc[2][0] = __builtin_amdgcn_mfma_f32_16x16x32_bf16(ai##2, bi##0, acc[2][0], 0, 0, 0); \
    acc[2][1] = __builtin_amdgcn_mfma_f32_16x16x32_bf16(ai##2, bi##1, acc[2][1], 0, 0, 0); \
    acc[2][2] = __builtin_amdgcn_mfma_f32_16x16x32_bf16(ai##2, bi##2, acc[2][2], 0, 0, 0); \
    acc[2][3] = __builtin_amdgcn_mfma_f32_16x16x32_bf16(ai##2, bi##3, acc[2][3], 0, 0, 0); \
    acc[3][0] = __builtin_amdgcn_mfma_f32_16x16x32_bf16(ai##3, bi##0, acc[3][0], 0, 0, 0); \
    acc[3][1] = __builtin_amdgcn_mfma_f32_16x16x32_bf16(ai##3, bi##1, acc[3][1], 0, 0, 0); \
    acc[3][2] = __builtin_amdgcn_mfma_f32_16x16x32_bf16(ai##3, bi##2, acc[3][2], 0, 0, 0); \
    acc[3][3] = __builtin_amdgcn_mfma_f32_16x16x32_bf16(ai##3, bi##3, acc[3][3], 0, 0, 0);

// ---------------- router: fp64-accurate logits, top-4, pack selection ----------------
__global__ __launch_bounds__(256) void router_kernel(
    const float* __restrict__ x, const float* __restrict__ Wr,
    const float* __restrict__ br, unsigned short* __restrict__ sel)
{
    const int tid = threadIdx.x;
    const int lt = tid & 63;
    const int wv = tid >> 6;
    const int tok = blockIdx.x * 4 + wv;
    const int e = lt >> 2, p = lt & 3;
    const float4* xp = (const float4*)(x + (size_t)tok * IN_F);
    const float4* wp = (const float4*)(Wr + (size_t)e * IN_F);
    double s = 0.0;
    for (int j = p; j < IN_F / 4; j += 4) {
        float4 a = xp[j], w = wp[j];
        s += (double)a.x * w.x + (double)a.y * w.y + (double)a.z * w.z + (double)a.w * w.w;
    }
    s += __shfl_down(s, 2);
    s += __shfl_down(s, 1);
    __shared__ double logits[4][NB];
    if (p == 0) logits[wv][e] = s + (double)br[e];
    __syncthreads();
    if (lt == 0) {
        unsigned used = 0, packed = 0;
        #pragma unroll
        for (int kk = 0; kk < 4; ++kk) {
            int best = 0; double bv = -1.0e300;
            #pragma unroll
            for (int i = 0; i < NB; ++i)
                if (!((used >> i) & 1u) && logits[wv][i] > bv) { bv = logits[wv][i]; best = i; }
            used |= 1u << best;
            packed |= (unsigned)best << (4 * kk);
        }
        sel[tok] = (unsigned short)packed;
    }
}

// ---------------- build per-expert token lists + inverse map (deterministic) ----------------
__global__ __launch_bounds__(256) void build_lists_kernel(
    const unsigned short* __restrict__ sel, int* __restrict__ counts,
    int* __restrict__ lists, unsigned* __restrict__ inv)
{
    const int e = blockIdx.x;
    const int t = threadIdx.x;
    unsigned short mysel[N_TOK / 256];
    int cnt = 0;
    #pragma unroll
    for (int i = 0; i < N_TOK / 256; ++i) {
        unsigned s = sel[i * 256 + t];
        mysel[i] = (unsigned short)s;
        bool m = ((s & 15u) == (unsigned)e) | (((s >> 4) & 15u) == (unsigned)e) |
                 (((s >> 8) & 15u) == (unsigned)e) | (((s >> 12) & 15u) == (unsigned)e);
        cnt += m ? 1 : 0;
    }
    __shared__ int ps[256];
    ps[t] = cnt;
    __syncthreads();
    #pragma unroll
    for (int off = 1; off < 256; off <<= 1) {
        int v = (t >= off) ? ps[t - off] : 0;
        __syncthreads();
        ps[t] += v;
        __syncthreads();
    }
    int pos = ps[t] - cnt;
    if (t == 255) counts[e] = ps[255];
    #pragma unroll
    for (int i = 0; i < N_TOK / 256; ++i) {
        unsigned s = mysel[i];
        bool m = ((s & 15u) == (unsigned)e) | (((s >> 4) & 15u) == (unsigned)e) |
                 (((s >> 8) & 15u) == (unsigned)e) | (((s >> 12) & 15u) == (unsigned)e);
        if (m) {
            const int tok = i * 256 + t;
            int j = ((s & 15u) == (unsigned)e) ? 0 :
                    (((s >> 4) & 15u) == (unsigned)e) ? 1 :
                    (((s >> 8) & 15u) == (unsigned)e) ? 2 : 3;
            inv[tok * 4 + j] = ((unsigned)e << 16) | (unsigned)pos;
            lists[e * N_TOK + pos++] = tok;
        }
    }
}

__global__ void scan_kernel(const int* __restrict__ counts, int* __restrict__ tstart)
{
    if (threadIdx.x == 0) {
        int acc = 0;
        for (int i = 0; i < NB; ++i) { tstart[i] = acc; acc += (counts[i] + BM - 1) / BM; }
        tstart[NB] = acc;
    }
}

// ---------------- W convert: fp32 -> bf16 with per-row XOR-swizzle of 16B k-slots ----------------
__global__ __launch_bounds__(256) void convert_w_kernel(
    const float* __restrict__ src, unsigned short* __restrict__ dst, int sh)
{
    const int total = 1 << 21;
    for (int id = blockIdx.x * 256 + threadIdx.x; id < total; id += 2048 * 256) {
        const int row = id >> sh;
        const int sr  = id & ((1 << sh) - 1);
        const int ps  = sr ^ (row & 7);
        const float4* s4 = (const float4*)(src + ((size_t)id << 3));
        float4 p0 = s4[0], p1 = s4[1];
        ushort8 o;
        o[0] = f2bf(p0.x); o[1] = f2bf(p0.y); o[2] = f2bf(p0.z); o[3] = f2bf(p0.w);
        o[4] = f2bf(p1.x); o[5] = f2bf(p1.y); o[6] = f2bf(p1.z); o[7] = f2bf(p1.w);
        *(ushort8*)(dst + (((size_t)(row) << sh) << 3) + ((size_t)ps << 3)) = o;
    }
}

// ---------------- gather-convert: xg[row] = bf16(x[lists[row]]), list-ordered, swizzled, zero pad ----------------
__global__ __launch_bounds__(256) void convert_gather_kernel(
    const float* __restrict__ x, const int* __restrict__ lists,
    const int* __restrict__ counts, const int* __restrict__ tstart,
    unsigned short* __restrict__ xg)
{
    const int row = blockIdx.x;
    const int mt = row >> 7;
    if (mt >= tstart[NB]) return;
    int b = 0;
    #pragma unroll
    for (int i = 1; i < NB; ++i) b += (mt >= tstart[i]);
    const int pos = row - tstart[b] * BM;
    const int t = threadIdx.x;                    // source 16B-slot index 0..255
    unsigned short* drow = xg + (size_t)row * IN_F;
    if (pos < counts[b]) {
        const int tok = lists[b * N_TOK + pos];
        const float4* s4 = (const float4*)(x + (size_t)tok * IN_F + t * 8);
        float4 p0 = s4[0], p1 = s4[1];
        ushort8 o;
        o[0] = f2bf(p0.x); o[1] = f2bf(p0.y); o[2] = f2bf(p0.z); o[3] = f2bf(p0.w);
        o[4] = f2bf(p1.x); o[5] = f2bf(p1.y); o[6] = f2bf(p1.z); o[7] = f2bf(p1.w);
        *(ushort8*)(drow + ((t ^ (row & 7)) << 3)) = o;
    } else {
        *(ushort8*)(drow + (t << 3)) = (ushort8)0;
    }
}

// ======== shared GEMM body: 128x128 tile, 4 waves, dbuf + counted vmcnt(8) ========
// A rows linear+pre-swizzled (xg or h); B rows pre-swizzled weights.

// ---------------- fc1: xg [Mg,2048] @ W1_b^T -> gelu -> h (bf16, pre-swizzled) ----------------
__global__ __launch_bounds__(256) void fc1_kernel(
    const unsigned short* __restrict__ xg, const unsigned short* __restrict__ w1_bf,
    const int* __restrict__ tstart, unsigned short* __restrict__ h)
{
    __shared__ unsigned short As[2][BM * 64];
    __shared__ unsigned short Bs[2][BM * 64];
    const int bid = blockIdx.x;
    const int newid = (bid & 7) * 136 + (bid >> 3);   // bijective: 1088 = 8*136
    const int nt = newid & 3, mt = newid >> 2;
    if (mt >= tstart[NB]) return;
    int b = 0;
    #pragma unroll
    for (int i = 1; i < NB; ++i) b += (mt >= tstart[i]);
    const int tid  = threadIdx.x;
    const int wave = tid >> 6, lane = tid & 63;
    const int sr8 = lane >> 3, sph = lane & 7;

    const unsigned short* aS[4];
    const unsigned short* bS[4];
    const int loff = wave * 2048;
    #pragma unroll
    for (int t = 0; t < 4; ++t) {
        const int r = wave * 32 + t * 8 + sr8;
        aS[t] = xg + (size_t)(mt * BM + r) * IN_F + (sph << 3);
        bS[t] = w1_bf + (size_t)(b * BS + nt * BM + r) * IN_F + (sph << 3);
    }

    const int lr16 = lane & 15, q = lane >> 4;
    const int wm = (wave >> 1) * 64, wn = (wave & 1) * 64;
    int offA[4], offB[4];
    #pragma unroll
    for (int i = 0; i < 4; ++i) { const int r = wm + i * 16 + lr16; offA[i] = r * 64 + ((q ^ (r & 7)) << 3); }
    #pragma unroll
    for (int j = 0; j < 4; ++j) { const int r = wn + j * 16 + lr16; offB[j] = r * 64 + ((q ^ (r & 7)) << 3); }

    f32x4 acc[4][4];
    #pragma unroll
    for (int i = 0; i < 4; ++i)
        #pragma unroll
        for (int j = 0; j < 4; ++j) acc[i][j] = (f32x4)0.0f;

    #pragma unroll
    for (int t = 0; t < 4; ++t) {
        gload16(aS[t], &As[0][loff + t * 512]);
        gload16(bS[t], &Bs[0][loff + t * 512]);
    }

    const int NK = IN_F / 64;
    for (int k = 0; k < NK; ++k) {
        const int cur = k & 1;
        if (k + 1 < NK) {
            const int ko = (k + 1) * 64;
            #pragma unroll
            for (int t = 0; t < 4; ++t) {
                gload16(aS[t] + ko, &As[cur ^ 1][loff + t * 512]);
                gload16(bS[t] + ko, &Bs[cur ^ 1][loff + t * 512]);
            }
            asm volatile("s_waitcnt vmcnt(8)" ::: "memory");
        } else {
            asm volatile("s_waitcnt vmcnt(0)" ::: "memory");
        }
        __builtin_amdgcn_s_barrier();
        __builtin_amdgcn_sched_barrier(0);
        {
            bf16x8 a0, a1, a2, a3, b0, b1, b2, b3;
            #pragma unroll
            for (int kk = 0; kk < 2; ++kk) {
                const int kx = kk << 5;
                a0 = *(const bf16x8*)&As[cur][offA[0] ^ kx];
                a1 = *(const bf16x8*)&As[cur][offA[1] ^ kx];
                a2 = *(const bf16x8*)&As[cur][offA[2] ^ kx];
                a3 = *(const bf16x8*)&As[cur][offA[3] ^ kx];
                b0 = *(const bf16x8*)&Bs[cur][offB[0] ^ kx];
                b1 = *(const bf16x8*)&Bs[cur][offB[1] ^ kx];
                b2 = *(const bf16x8*)&Bs[cur][offB[2] ^ kx];
                b3 = *(const bf16x8*)&Bs[cur][offB[3] ^ kx];
                __builtin_amdgcn_s_setprio(1);
                MFMA16(a, b)
                __builtin_amdgcn_s_setprio(0);
            }
        }
        __builtin_amdgcn_sched_barrier(0);
        __builtin_amdgcn_s_barrier();
    }
    // epilogue: exact gelu, store h pre-swizzled by row&7 (pad rows are zeros -> safe)
    #pragma unroll
    for (int i = 0; i < 4; ++i) {
        #pragma unroll
        for (int r = 0; r < 4; ++r) {
            const int lrow = wm + i * 16 + q * 4 + r;
            const size_t hrow = (size_t)(mt * BM + lrow) * BS;
            const int r7 = (lrow & 7) << 3;
            #pragma unroll
            for (int j = 0; j < 4; ++j) {
                const int col = nt * BM + wn + j * 16 + lr16;
                float v = acc[i][j][r];
                v = 0.5f * v * (1.0f + erff(v * 0.70710678118654752f));
                h[hrow + (col ^ r7)] = f2bf(v);
            }
        }
    }
}

// ---------------- fc2: h [Mg,512] @ W2_b^T -> yp (fp16 partials, list order) ----------------
__global__ __launch_bounds__(256) void fc2_kernel(
    const unsigned short* __restrict__ h, const unsigned short* __restrict__ w2_bf,
    const int* __restrict__ tstart, _Float16* __restrict__ yp)
{
    __shared__ unsigned short As[2][BM * 64];
    __shared__ unsigned short Bs[2][BM * 64];
    const int bid = blockIdx.x;
    const int newid = (bid & 7) * 544 + (bid >> 3);   // bijective: 4352 = 8*544
    const int nt = newid & 15, mt = newid >> 4;
    if (mt >= tstart[NB]) return;
    int b = 0;
    #pragma unroll
    for (int i = 1; i < NB; ++i) b += (mt >= tstart[i]);
    const int tid  = threadIdx.x;
    const int wave = tid >> 6, lane = tid & 63;
    const int sr8 = lane >> 3, sph = lane & 7;

    const unsigned short* aS[4];
    const unsigned short* bS[4];
    const int loff = wave * 2048;
    #pragma unroll
    for (int t = 0; t < 4; ++t) {
        const int r = wave * 32 + t * 8 + sr8;
        aS[t] = h + (size_t)(mt * BM + r) * BS + (sph << 3);
        bS[t] = w2_bf + (size_t)(nt * BM + r) * OUT_F + b * BS + (sph << 3);
    }

    const int lr16 = lane & 15, q = lane >> 4;
    const int wm = (wave >> 1) * 64, wn = (wave & 1) * 64;
    int offA[4], offB[4];
    #pragma unroll
    for (int i = 0; i < 4; ++i) { const int r = wm + i * 16 + lr16; offA[i] = r * 64 + ((q ^ (r & 7)) << 3); }
    #pragma unroll
    for (int j = 0; j < 4; ++j) { const int r = wn + j * 16 + lr16; offB[j] = r * 64 + ((q ^ (r & 7)) << 3); }

    f32x4 acc[4][4];
    #pragma unroll
    for (int i = 0; i < 4; ++i)
        #pragma unroll
        for (int j = 0; j < 4; ++j) acc[i][j] = (f32x4)0.0f;

    #pragma unroll
    for (int t = 0; t < 4; ++t) {
        gload16(aS[t], &As[0][loff + t * 512]);
        gload16(bS[t], &Bs[0][loff + t * 512]);
    }

    const int NK = BS / 64;
    for (int k = 0; k < NK; ++k) {
        const int cur = k & 1;
        if (k + 1 < NK) {
            const int ko = (k + 1) * 64;
            #pragma unroll
            for (int t = 0; t < 4; ++t) {
                gload16(aS[t] + ko, &As[cur ^ 1][loff + t * 512]);
                gload16(bS[t] + ko, &Bs[cur ^ 1][loff + t * 512]);
            }
            asm volatile("s_waitcnt vmcnt(8)" ::: "memory");
        } else {
            asm volatile("s_waitcnt vmcnt(0)" ::: "memory");
        }
        __builtin_amdgcn_s_barrier();
        __builtin_amdgcn_sched_barrier(0);
        {
            bf16x8 a0, a1, a2, a3, b0, b1, b2, b3;
            #pragma unroll
            for (int kk = 0; kk < 2; ++kk) {
                const int kx = kk << 5;
                a0 = *(const bf16x8*)&As[cur][offA[0] ^ kx];
                a1 = *(const bf16x8*)&As[cur][offA[1] ^ kx];
                a2 = *(const bf16x8*)&As[cur][offA[2] ^ kx];
                a3 = *(const bf16x8*)&As[cur][offA[3] ^ kx];
                b0 = *(const bf16x8*)&Bs[cur][offB[0] ^ kx];
                b1 = *(const bf16x8*)&Bs[cur][offB[1] ^ kx];
                b2 = *(const bf16x8*)&Bs[cur][offB[2] ^ kx];
                b3 = *(const bf16x8*)&Bs[cur][offB[3] ^ kx];
                __builtin_amdgcn_s_setprio(1);
                MFMA16(a, b)
                __builtin_amdgcn_s_setprio(0);
            }
        }
        __builtin_amdgcn_sched_barrier(0);
        __builtin_amdgcn_s_barrier();
    }
    // epilogue: store fp16 partials (pad rows harmless -- never read by reduce)
    #pragma unroll
    for (int i = 0; i < 4; ++i) {
        #pragma unroll
        for (int r = 0; r < 4; ++r) {
            const int lrow = wm + i * 16 + q * 4 + r;
            _Float16* yrow = yp + (size_t)(mt * BM + lrow) * IN_F + nt * BM + wn + lr16;
            #pragma unroll
            for (int j = 0; j < 4; ++j)
                yrow[j * 16] = (_Float16)acc[i][j][r];
        }
    }
}

// ---------------- reduce: y[t] = sum of the token's 4 fp16 partial rows ----------------
__global__ __launch_bounds__(256) void reduce_kernel(
    const _Float16* __restrict__ yp, const unsigned* __restrict__ inv,
    const int* __restrict__ tstart, float* __restrict__ y)
{
    const int tok = blockIdx.x;
    __shared__ size_t rbase[4];
    if (threadIdx.x < 4) {
        unsigned v = inv[tok * 4 + threadIdx.x];
        rbase[threadIdx.x] = (size_t)(tstart[v >> 16] * BM + (int)(v & 0xFFFFu)) * IN_F;
    }
    __syncthreads();
    const int c = threadIdx.x * 8;
    f16x8 v0 = *(const f16x8*)(yp + rbase[0] + c);
    f16x8 v1 = *(const f16x8*)(yp + rbase[1] + c);
    f16x8 v2 = *(const f16x8*)(yp + rbase[2] + c);
    f16x8 v3 = *(const f16x8*)(yp + rbase[3] + c);
    float out[8];
    #pragma unroll
    for (int j = 0; j < 8; ++j)
        out[j] = (float)v0[j] + (float)v1[j] + (float)v2[j] + (float)v3[j];
    float4* yo = (float4*)(y + (size_t)tok * IN_F + c);
    yo[0] = make_float4(out[0], out[1], out[2], out[3]);
    yo[1] = make_float4(out[4], out[5], out[6], out[7]);
}

extern "C" void kernel_launch(void* const* d_in, const int* in_sizes, int n_in,
                              void* d_out, int out_size, void* d_ws, size_t ws_size,
                              hipStream_t stream) {
    const float* x  = (const float*)d_in[0];
    const float* Wr = (const float*)d_in[1];
    const float* br = (const float*)d_in[2];
    const float* W1 = (const float*)d_in[3];
    const float* W2 = (const float*)d_in[4];
    float* y = (float*)d_out;
    char* ws = (char*)d_ws;
    int* counts = (int*)(ws + WS_COUNTS);
    int* tstart = (int*)(ws + WS_TSTART);
    unsigned short* sel = (unsigned short*)(ws + WS_SEL);
    unsigned* inv = (unsigned*)(ws + WS_INV);
    int* lists  = (int*)(ws + WS_LISTS);
    unsigned short* xg    = (unsigned short*)(ws + WS_XG);
    unsigned short* w1_bf = (unsigned short*)(ws + WS_W1BF);
    unsigned short* w2_bf = (unsigned short*)(ws + WS_W2BF);
    unsigned short* h     = (unsigned short*)(ws + WS_H);
    _Float16* yp          = (_Float16*)(ws + WS_YP);

    hipLaunchKernelGGL(router_kernel, dim3(N_TOK / 4), dim3(256), 0, stream, x, Wr, br, sel);
    hipLaunchKernelGGL(build_lists_kernel, dim3(NB), dim3(256), 0, stream, sel, counts, lists, inv);
    hipLaunchKernelGGL(scan_kernel, dim3(1), dim3(64), 0, stream, counts, tstart);
    hipLaunchKernelGGL(convert_w_kernel, dim3(2048), dim3(256), 0, stream, W1, w1_bf, 8);
    hipLaunchKernelGGL(convert_gather_kernel, dim3(MAX_MT * BM), dim3(256), 0, stream, x, lists, counts, tstart, xg);
    hipLaunchKernelGGL(fc1_kernel, dim3(4 * MAX_MT), dim3(256), 0, stream, xg, w1_bf, tstart, h);
    hipLaunchKernelGGL(convert_w_kernel, dim3(2048), dim3(256), 0, stream, W2, w2_bf, 10);
    hipLaunchKernelGGL(fc2_kernel, dim3(16 * MAX_MT), dim3(256), 0, stream, h, w2_bf, tstart, yp);
    hipLaunchKernelGGL(reduce_kernel, dim3(N_TOK), dim3(256), 0, stream, yp, inv, tstart, y);
}

// Round 12
// 409.291 us; speedup vs baseline: 1.3076x; 1.2351x over previous
//
#include <hip/hip_runtime.h>
#include <hip/hip_bf16.h>

#define N_TOK 8192
#define IN_F  2048
#define OUT_F 8192
#define NB    16
#define BS    512
#define BM2   256
#define MAX_MT2 144         // worst-case 256-row M-tiles: 32768/256 + 16

typedef short          bf16x8  __attribute__((ext_vector_type(8)));
typedef unsigned short ushort8 __attribute__((ext_vector_type(8)));
typedef float          f32x4   __attribute__((ext_vector_type(4)));
typedef _Float16       f16x8   __attribute__((ext_vector_type(8)));

// ws layout (peak ~223 MB, proven in R8)
#define WS_COUNTS 0
#define WS_TSTART 64
#define WS_SEL    256                           // 8192 u16
#define WS_INV    (32*1024)                     // 8192*4 u32
#define WS_LISTS  (192*1024)                    // 16*8192 int
#define WS_XBF    (1ull<<20)                    // x_bf 32MB (w2_bf aliases after fc1)
#define WS_W2BF   WS_XBF
#define WS_H      (WS_XBF + 33554432ull)        // h: 36864*512*2 = 36MB
#define WS_W1BF   (WS_H + 37748736ull)          // w1_bf 32MB (dead after fc1)
#define WS_YP     WS_W1BF                       // yp: 36864*2048*2 = 144MB, overlays w1_bf

static __device__ __forceinline__ unsigned short f2bf(float f) {
    __hip_bfloat16 h = __float2bfloat16(f);
    return *reinterpret_cast<unsigned short*>(&h);
}

static __device__ __forceinline__ void gload16(const unsigned short* g, unsigned short* lds) {
    __builtin_amdgcn_global_load_lds(
        (const __attribute__((address_space(1))) unsigned int*)g,
        (__attribute__((address_space(3))) unsigned int*)lds, 16, 0, 0);
}

#define MFMA16(ai, bi) \
    acc[0][0] = __builtin_amdgcn_mfma_f32_16x16x32_bf16(ai##0, bi##0, acc[0][0], 0, 0, 0); \
    acc[0][1] = __builtin_amdgcn_mfma_f32_16x16x32_bf16(ai##0, bi##1, acc[0][1], 0, 0, 0); \
    acc[0][2] = __builtin_amdgcn_mfma_f32_16x16x32_bf16(ai##0, bi##2, acc[0][2], 0, 0, 0); \
    acc[0][3] = __builtin_amdgcn_mfma_f32_16x16x32_bf16(ai##0, bi##3, acc[0][3], 0, 0, 0); \
    acc[1][0] = __builtin_amdgcn_mfma_f32_16x16x32_bf16(ai##1, bi##0, acc[1][0], 0, 0, 0); \
    acc[1][1] = __builtin_amdgcn_mfma_f32_16x16x32_bf16(ai##1, bi##1, acc[1][1], 0, 0, 0); \
    acc[1][2] = __builtin_amdgcn_mfma_f32_16x16x32_bf16(ai##1, bi##2, acc[1][2], 0, 0, 0); \
    acc[1][3] = __builtin_amdgcn_mfma_f32_16x16x32_bf16(ai##1, bi##3, acc[1][3], 0, 0, 0); \
    acc[2][0] = __builtin_amdgcn_mfma_f32_16x16x32_bf16(ai##2, bi##0, acc[2][0], 0, 0, 0); \
    acc[2][1] = __builtin_amdgcn_mfma_f32_16x16x32_bf16(ai##2, bi##1, acc[2][1], 0, 0, 0); \
    acc[2][2] = __builtin_amdgcn_mfma_f32_16x16x32_bf16(ai##2, bi##2, acc[2][2], 0, 0, 0); \
    acc[2][3] = __builtin_amdgcn_mfma_f32_16x16x32_bf16(ai##2, bi##3, acc[2][3], 0, 0, 0); \
    acc[3][0] = __builtin_amdgcn_mfma_f32_16x16x32_bf16(ai##3, bi##0, acc[3][0], 0, 0, 0); \
    acc[3][1] = __builtin_amdgcn_mfma_f32_16x16x32_bf16(ai##3, bi##1, acc[3][1], 0, 0, 0); \
    acc[3][2] = __builtin_amdgcn_mfma_f32_16x16x32_bf16(ai##3, bi##2, acc[3][2], 0, 0, 0); \
    acc[3][3] = __builtin_amdgcn_mfma_f32_16x16x32_bf16(ai##3, bi##3, acc[3][3], 0, 0, 0);

#define PHASE_TAIL \
    __builtin_amdgcn_s_barrier(); \
    asm volatile("s_waitcnt lgkmcnt(0)" ::: "memory"); \
    __builtin_amdgcn_sched_barrier(0); \
    __builtin_amdgcn_s_setprio(1); \
    MFMA16(a, b) \
    __builtin_amdgcn_s_setprio(0); \
    __builtin_amdgcn_sched_barrier(0); \
    __builtin_amdgcn_s_barrier();

// ---------------- router: LDS-staged x row, fp64 logits, top-4 ----------------
__global__ __launch_bounds__(256) void router_kernel(
    const float* __restrict__ x, const float* __restrict__ Wr,
    const float* __restrict__ br, unsigned short* __restrict__ sel)
{
    __shared__ float xs[4][IN_F];
    const int tid = threadIdx.x;
    const int lt = tid & 63;
    const int wv = tid >> 6;
    const int tok = blockIdx.x * 4 + wv;
    float4* xl = (float4*)xs[wv];
    const float4* xp = (const float4*)(x + (size_t)tok * IN_F);
    #pragma unroll
    for (int i = 0; i < 8; ++i) xl[lt + i * 64] = xp[lt + i * 64];
    __syncthreads();
    const int e = lt >> 2, p = lt & 3;
    const float4* wp = (const float4*)(Wr + (size_t)e * IN_F);
    double s = 0.0;
    for (int j = p; j < IN_F / 4; j += 4) {
        float4 a = xl[j], w = wp[j];
        s += (double)a.x * w.x + (double)a.y * w.y + (double)a.z * w.z + (double)a.w * w.w;
    }
    s += __shfl_down(s, 2);
    s += __shfl_down(s, 1);
    __shared__ double logits[4][NB];
    if (p == 0) logits[wv][e] = s + (double)br[e];
    __syncthreads();
    if (lt == 0) {
        unsigned used = 0, packed = 0;
        #pragma unroll
        for (int kk = 0; kk < 4; ++kk) {
            int best = 0; double bv = -1.0e300;
            #pragma unroll
            for (int i = 0; i < NB; ++i)
                if (!((used >> i) & 1u) && logits[wv][i] > bv) { bv = logits[wv][i]; best = i; }
            used |= 1u << best;
            packed |= (unsigned)best << (4 * kk);
        }
        sel[tok] = (unsigned short)packed;
    }
}

// ---------------- build per-expert token lists + inverse map (deterministic) ----------------
__global__ __launch_bounds__(256) void build_lists_kernel(
    const unsigned short* __restrict__ sel, int* __restrict__ counts,
    int* __restrict__ lists, unsigned* __restrict__ inv)
{
    const int e = blockIdx.x;
    const int t = threadIdx.x;
    unsigned short mysel[N_TOK / 256];
    int cnt = 0;
    #pragma unroll
    for (int i = 0; i < N_TOK / 256; ++i) {
        unsigned s = sel[i * 256 + t];
        mysel[i] = (unsigned short)s;
        bool m = ((s & 15u) == (unsigned)e) | (((s >> 4) & 15u) == (unsigned)e) |
                 (((s >> 8) & 15u) == (unsigned)e) | (((s >> 12) & 15u) == (unsigned)e);
        cnt += m ? 1 : 0;
    }
    __shared__ int ps[256];
    ps[t] = cnt;
    __syncthreads();
    #pragma unroll
    for (int off = 1; off < 256; off <<= 1) {
        int v = (t >= off) ? ps[t - off] : 0;
        __syncthreads();
        ps[t] += v;
        __syncthreads();
    }
    int pos = ps[t] - cnt;
    if (t == 255) counts[e] = ps[255];
    #pragma unroll
    for (int i = 0; i < N_TOK / 256; ++i) {
        unsigned s = mysel[i];
        bool m = ((s & 15u) == (unsigned)e) | (((s >> 4) & 15u) == (unsigned)e) |
                 (((s >> 8) & 15u) == (unsigned)e) | (((s >> 12) & 15u) == (unsigned)e);
        if (m) {
            const int tok = i * 256 + t;
            int j = ((s & 15u) == (unsigned)e) ? 0 :
                    (((s >> 4) & 15u) == (unsigned)e) ? 1 :
                    (((s >> 8) & 15u) == (unsigned)e) ? 2 : 3;
            inv[tok * 4 + j] = ((unsigned)e << 16) | (unsigned)pos;
            lists[e * N_TOK + pos++] = tok;
        }
    }
}

__global__ void scan_kernel(const int* __restrict__ counts, int* __restrict__ tstart)
{
    if (threadIdx.x == 0) {
        int acc = 0;
        for (int i = 0; i < NB; ++i) { tstart[i] = acc; acc += (counts[i] + BM2 - 1) / BM2; }
        tstart[NB] = acc;
    }
}

// ---------------- fp32 -> bf16 convert with per-row XOR-swizzle of 16B k-slots ----------------
__global__ __launch_bounds__(256) void convert_swz_kernel(
    const float* __restrict__ src, unsigned short* __restrict__ dst, int sh)
{
    const int total = 1 << 21;
    for (int id = blockIdx.x * 256 + threadIdx.x; id < total; id += 2048 * 256) {
        const int row = id >> sh;
        const int sr  = id & ((1 << sh) - 1);
        const int ps  = sr ^ (row & 7);
        const float4* s4 = (const float4*)(src + ((size_t)id << 3));
        float4 p0 = s4[0], p1 = s4[1];
        ushort8 o;
        o[0] = f2bf(p0.x); o[1] = f2bf(p0.y); o[2] = f2bf(p0.z); o[3] = f2bf(p0.w);
        o[4] = f2bf(p1.x); o[5] = f2bf(p1.y); o[6] = f2bf(p1.z); o[7] = f2bf(p1.w);
        *(ushort8*)(dst + (((size_t)(row) << sh) << 3) + ((size_t)ps << 3)) = o;
    }
}

// ======== fc1: 256x128 tile, 8 waves, triple-buffered phase-interleaved K-loop (R8, best measured) ========
__global__ __launch_bounds__(512) void fc1_kernel(
    const unsigned short* __restrict__ x_bf, const unsigned short* __restrict__ w1_bf,
    const int* __restrict__ lists, const int* __restrict__ counts,
    const int* __restrict__ tstart, unsigned short* __restrict__ h)
{
    __shared__ unsigned short lds[73728];   // 3 x (A 32KB + B 16KB) = 144KB
    const int bid = blockIdx.x;
    const int newid = (bid & 7) * 72 + (bid >> 3);   // bijective: 576 = 8*72
    const int nt = newid & 3, mt = newid >> 2;
    if (mt >= tstart[NB]) return;
    int b = 0;
    #pragma unroll
    for (int i = 1; i < NB; ++i) b += (mt >= tstart[i]);
    const int cnt  = counts[b];
    const int row0 = (mt - tstart[b]) * BM2;
    const int tid  = threadIdx.x;
    const int wave = tid >> 6, lane = tid & 63;
    const int sph = lane & 7;
    const int rbase = wave * 8 + (lane >> 3);        // 0..63

    const unsigned short* aS[4];
    const unsigned short* bS[2];
    #pragma unroll
    for (int i = 0; i < 4; ++i) {
        const int r = i * 64 + rbase;
        const int gr = min(row0 + r, cnt - 1);
        const int tok = lists[b * N_TOK + gr];
        aS[i] = x_bf + (size_t)tok * IN_F + ((sph ^ (r & 7) ^ (tok & 7)) << 3);
    }
    #pragma unroll
    for (int j = 0; j < 2; ++j) {
        const int r = j * 64 + rbase;
        bS[j] = w1_bf + (size_t)(b * BS + nt * 128 + r) * IN_F + (sph << 3);
    }
    const int wbase = wave * 512;

    const int lr16 = lane & 15, q = lane >> 4;
    const int wm = (wave >> 1) * 64, wn = (wave & 1) * 64;
    int offA[4], offB[4];
    #pragma unroll
    for (int i = 0; i < 4; ++i) { const int r = wm + i * 16 + lr16; offA[i] = r * 64 + ((q ^ (r & 7)) << 3); }
    #pragma unroll
    for (int j = 0; j < 4; ++j) { const int r = wn + j * 16 + lr16; offB[j] = r * 64 + ((q ^ (r & 7)) << 3); }

    f32x4 acc[4][4];
    #pragma unroll
    for (int i = 0; i < 4; ++i)
        #pragma unroll
        for (int j = 0; j < 4; ++j) acc[i][j] = (f32x4)0.0f;

#define STA1(k, buf, i) gload16(aS[i] + (size_t)(k) * 64, lds + (buf) * 24576 + (i) * 4096 + wbase)
#define STB1(k, buf, j) gload16(bS[j] + (size_t)(k) * 64, lds + (buf) * 24576 + 16384 + (j) * 4096 + wbase)

    STA1(0,0,0); STA1(0,0,1); STA1(0,0,2); STA1(0,0,3); STB1(0,0,0); STB1(0,0,1);
    STA1(1,1,0); STA1(1,1,1); STA1(1,1,2); STA1(1,1,3); STB1(1,1,0); STB1(1,1,1);
    asm volatile("s_waitcnt vmcnt(6)" ::: "memory");
    __builtin_amdgcn_s_barrier();

    const int NK = IN_F / 64;   // 32
    int cur = 0;
    for (int k = 0; k < NK; ++k) {
        const unsigned short* Ab = lds + cur * 24576;
        const unsigned short* Bb = Ab + 16384;
        const int nxt = (cur == 0) ? 2 : cur - 1;    // (cur+2)%3
        bf16x8 a0 = *(const bf16x8*)&Ab[offA[0]];
        bf16x8 a1 = *(const bf16x8*)&Ab[offA[1]];
        bf16x8 a2 = *(const bf16x8*)&Ab[offA[2]];
        bf16x8 a3 = *(const bf16x8*)&Ab[offA[3]];
        bf16x8 b0 = *(const bf16x8*)&Bb[offB[0]];
        bf16x8 b1 = *(const bf16x8*)&Bb[offB[1]];
        bf16x8 b2 = *(const bf16x8*)&Bb[offB[2]];
        bf16x8 b3 = *(const bf16x8*)&Bb[offB[3]];
        if (k + 2 < NK) { STA1(k + 2, nxt, 0); STA1(k + 2, nxt, 1); STB1(k + 2, nxt, 0); }
        PHASE_TAIL
        a0 = *(const bf16x8*)&Ab[offA[0] ^ 32];
        a1 = *(const bf16x8*)&Ab[offA[1] ^ 32];
        a2 = *(const bf16x8*)&Ab[offA[2] ^ 32];
        a3 = *(const bf16x8*)&Ab[offA[3] ^ 32];
        b0 = *(const bf16x8*)&Bb[offB[0] ^ 32];
        b1 = *(const bf16x8*)&Bb[offB[1] ^ 32];
        b2 = *(const bf16x8*)&Bb[offB[2] ^ 32];
        b3 = *(const bf16x8*)&Bb[offB[3] ^ 32];
        if (k + 2 < NK) {
            STA1(k + 2, nxt, 2); STA1(k + 2, nxt, 3); STB1(k + 2, nxt, 1);
            asm volatile("s_waitcnt vmcnt(6)" ::: "memory");
        } else if (k + 1 < NK) {
            asm volatile("s_waitcnt vmcnt(0)" ::: "memory");
        }
        PHASE_TAIL
        cur = (cur == 2) ? 0 : cur + 1;
    }
    // epilogue: exact gelu, store h pre-swizzled by row&7 (16B-slot XOR)
    #pragma unroll
    for (int i = 0; i < 4; ++i) {
        #pragma unroll
        for (int r = 0; r < 4; ++r) {
            const int lrow = wm + i * 16 + q * 4 + r;
            if (row0 + lrow < cnt) {
                const size_t hrow = (size_t)(mt * BM2 + lrow) * BS;
                const int r7 = (lrow & 7) << 3;
                #pragma unroll
                for (int j = 0; j < 4; ++j) {
                    const int col = nt * 128 + wn + j * 16 + lr16;
                    float v = acc[i][j][r];
                    v = 0.5f * v * (1.0f + erff(v * 0.70710678118654752f));
                    h[hrow + (col ^ r7)] = f2bf(v);
                }
            }
        }
    }
#undef STA1
#undef STB1
}

// ======== fc2: 256x256 tile, 8 waves (2x4), 2-buffer phase-interleaved; h @ W2_b^T -> yp fp16 ========
// RACE FIX vs R11: vmcnt(0) for tile k+1 staging sits BEFORE phase-B's barrier, so
// barrier-exit guarantees all waves' staging landed before the next iteration's ds_reads.
__global__ __launch_bounds__(512) void fc2_kernel(
    const unsigned short* __restrict__ h, const unsigned short* __restrict__ w2_bf,
    const int* __restrict__ counts, const int* __restrict__ tstart,
    _Float16* __restrict__ yp)
{
    __shared__ unsigned short lds[2][32768];   // per buf: A 32KB + B 32KB
    const int bid = blockIdx.x;
    const int newid = (bid & 7) * 144 + (bid >> 3);  // bijective: 1152 = 8*144
    const int nt = newid & 7, mt = newid >> 3;
    if (mt >= tstart[NB]) return;
    int b = 0;
    #pragma unroll
    for (int i = 1; i < NB; ++i) b += (mt >= tstart[i]);
    const int cnt  = counts[b];
    const int row0 = (mt - tstart[b]) * BM2;
    const int tid  = threadIdx.x;
    const int wave = tid >> 6, lane = tid & 63;
    const int sph = lane & 7;
    const int rbase = wave * 8 + (lane >> 3);        // 0..63

    const unsigned short* aS[4];
    const unsigned short* bS[4];
    #pragma unroll
    for (int g = 0; g < 4; ++g) {
        const int r = g * 64 + rbase;
        aS[g] = h + (size_t)(mt * BM2 + r) * BS + (sph << 3);
        bS[g] = w2_bf + (size_t)(nt * 256 + r) * OUT_F + b * BS + (sph << 3);
    }
    const int wbase = wave * 512;

    const int lr16 = lane & 15, q = lane >> 4;
    const int wr = (wave >> 2) * 128, wc = (wave & 3) * 64;
    int offA[8], offB[4];
    #pragma unroll
    for (int i = 0; i < 8; ++i) { const int r = wr + i * 16 + lr16; offA[i] = r * 64 + ((q ^ (r & 7)) << 3); }
    #pragma unroll
    for (int j = 0; j < 4; ++j) { const int r = wc + j * 16 + lr16; offB[j] = 16384 + r * 64 + ((q ^ (r & 7)) << 3); }

    f32x4 acc[8][4];
    #pragma unroll
    for (int i = 0; i < 8; ++i)
        #pragma unroll
        for (int j = 0; j < 4; ++j) acc[i][j] = (f32x4)0.0f;

#define ST2(k, buf) \
    { _Pragma("unroll") for (int g = 0; g < 4; ++g) \
        gload16(aS[g] + (size_t)(k) * 64, &lds[buf][g * 4096 + wbase]); \
      _Pragma("unroll") for (int g = 0; g < 4; ++g) \
        gload16(bS[g] + (size_t)(k) * 64, &lds[buf][16384 + g * 4096 + wbase]); }

#define MFMA_8x4 \
    __builtin_amdgcn_s_barrier(); \
    asm volatile("s_waitcnt lgkmcnt(0)" ::: "memory"); \
    __builtin_amdgcn_sched_barrier(0); \
    __builtin_amdgcn_s_setprio(1); \
    _Pragma("unroll") for (int i = 0; i < 8; ++i) \
        _Pragma("unroll") for (int j = 0; j < 4; ++j) \
            acc[i][j] = __builtin_amdgcn_mfma_f32_16x16x32_bf16(a[i], bb[j], acc[i][j], 0, 0, 0); \
    __builtin_amdgcn_s_setprio(0); \
    __builtin_amdgcn_sched_barrier(0); \
    __builtin_amdgcn_s_barrier();

    ST2(0, 0);
    asm volatile("s_waitcnt vmcnt(0)" ::: "memory");
    __builtin_amdgcn_s_barrier();

    const int NK = BS / 64;   // 8
    for (int k = 0; k < NK; ++k) {
        const int cur = k & 1;
        const unsigned short* L = lds[cur];
        // phase A: ds_read half0, issue ALL of tile k+1's staging
        {
            bf16x8 a[8], bb[4];
            #pragma unroll
            for (int i = 0; i < 8; ++i) a[i]  = *(const bf16x8*)&L[offA[i]];
            #pragma unroll
            for (int j = 0; j < 4; ++j) bb[j] = *(const bf16x8*)&L[offB[j]];
            if (k + 1 < NK) ST2(k + 1, cur ^ 1);
            MFMA_8x4
        }
        // phase B: ds_read half1; drain staging BEFORE the barrier (correctness-critical)
        {
            bf16x8 a[8], bb[4];
            #pragma unroll
            for (int i = 0; i < 8; ++i) a[i]  = *(const bf16x8*)&L[offA[i] ^ 32];
            #pragma unroll
            for (int j = 0; j < 4; ++j) bb[j] = *(const bf16x8*)&L[offB[j] ^ 32];
            if (k + 1 < NK) asm volatile("s_waitcnt vmcnt(0)" ::: "memory");
            MFMA_8x4
        }
    }
    // epilogue: store fp16 partials
    #pragma unroll
    for (int i = 0; i < 8; ++i) {
        #pragma unroll
        for (int r = 0; r < 4; ++r) {
            const int lrow = wr + i * 16 + q * 4 + r;
            if (row0 + lrow < cnt) {
                _Float16* yrow = yp + (size_t)(mt * BM2 + lrow) * IN_F + nt * 256 + wc + lr16;
                #pragma unroll
                for (int j = 0; j < 4; ++j)
                    yrow[j * 16] = (_Float16)acc[i][j][r];
            }
        }
    }
#undef ST2
#undef MFMA_8x4
}

// ---------------- reduce: y[t] = sum of the token's 4 fp16 partial rows ----------------
__global__ __launch_bounds__(256) void reduce_kernel(
    const _Float16* __restrict__ yp, const unsigned* __restrict__ inv,
    const int* __restrict__ tstart, float* __restrict__ y)
{
    const int tok = blockIdx.x;
    __shared__ size_t rbase[4];
    if (threadIdx.x < 4) {
        unsigned v = inv[tok * 4 + threadIdx.x];
        rbase[threadIdx.x] = (size_t)(tstart[v >> 16] * BM2 + (int)(v & 0xFFFFu)) * IN_F;
    }
    __syncthreads();
    const int c = threadIdx.x * 8;
    f16x8 v0 = *(const f16x8*)(yp + rbase[0] + c);
    f16x8 v1 = *(const f16x8*)(yp + rbase[1] + c);
    f16x8 v2 = *(const f16x8*)(yp + rbase[2] + c);
    f16x8 v3 = *(const f16x8*)(yp + rbase[3] + c);
    float out[8];
    #pragma unroll
    for (int j = 0; j < 8; ++j)
        out[j] = (float)v0[j] + (float)v1[j] + (float)v2[j] + (float)v3[j];
    float4* yo = (float4*)(y + (size_t)tok * IN_F + c);
    yo[0] = make_float4(out[0], out[1], out[2], out[3]);
    yo[1] = make_float4(out[4], out[5], out[6], out[7]);
}

extern "C" void kernel_launch(void* const* d_in, const int* in_sizes, int n_in,
                              void* d_out, int out_size, void* d_ws, size_t ws_size,
                              hipStream_t stream) {
    const float* x  = (const float*)d_in[0];
    const float* Wr = (const float*)d_in[1];
    const float* br = (const float*)d_in[2];
    const float* W1 = (const float*)d_in[3];
    const float* W2 = (const float*)d_in[4];
    float* y = (float*)d_out;
    char* ws = (char*)d_ws;
    int* counts = (int*)(ws + WS_COUNTS);
    int* tstart = (int*)(ws + WS_TSTART);
    unsigned short* sel = (unsigned short*)(ws + WS_SEL);
    unsigned* inv = (unsigned*)(ws + WS_INV);
    int* lists  = (int*)(ws + WS_LISTS);
    unsigned short* x_bf  = (unsigned short*)(ws + WS_XBF);
    unsigned short* w1_bf = (unsigned short*)(ws + WS_W1BF);
    unsigned short* w2_bf = (unsigned short*)(ws + WS_W2BF);
    unsigned short* h     = (unsigned short*)(ws + WS_H);
    _Float16* yp          = (_Float16*)(ws + WS_YP);

    hipLaunchKernelGGL(router_kernel, dim3(N_TOK / 4), dim3(256), 0, stream, x, Wr, br, sel);
    hipLaunchKernelGGL(build_lists_kernel, dim3(NB), dim3(256), 0, stream, sel, counts, lists, inv);
    hipLaunchKernelGGL(scan_kernel, dim3(1), dim3(64), 0, stream, counts, tstart);
    hipLaunchKernelGGL(convert_swz_kernel, dim3(2048), dim3(256), 0, stream, x,  x_bf,  8);
    hipLaunchKernelGGL(convert_swz_kernel, dim3(2048), dim3(256), 0, stream, W1, w1_bf, 8);
    hipLaunchKernelGGL(fc1_kernel, dim3(4 * MAX_MT2), dim3(512), 0, stream, x_bf, w1_bf, lists, counts, tstart, h);
    hipLaunchKernelGGL(convert_swz_kernel, dim3(2048), dim3(256), 0, stream, W2, w2_bf, 10);
    hipLaunchKernelGGL(fc2_kernel, dim3(8 * MAX_MT2), dim3(512), 0, stream, h, w2_bf, counts, tstart, yp);
    hipLaunchKernelGGL(reduce_kernel, dim3(N_TOK), dim3(256), 0, stream, yp, inv, tstart, y);
}

// Round 14
// 397.462 us; speedup vs baseline: 1.3465x; 1.0298x over previous
//
#include <hip/hip_runtime.h>
#include <hip/hip_bf16.h>

#define N_TOK 8192
#define IN_F  2048
#define OUT_F 8192
#define NB    16
#define BS    512
#define BM2   256
#define MAX_MT2 144         // worst-case 256-row M-tiles: 32768/256 + 16

typedef short          bf16x8  __attribute__((ext_vector_type(8)));
typedef unsigned short ushort8 __attribute__((ext_vector_type(8)));
typedef float          f32x4   __attribute__((ext_vector_type(4)));
typedef _Float16       f16x8   __attribute__((ext_vector_type(8)));

// ws layout (peak ~223 MB, identical to R12-green)
#define WS_COUNTS 0
#define WS_TSTART 64
#define WS_SEL    256                           // 8192 u16
#define WS_INV    (32*1024)                     // 8192*4 u32
#define WS_LISTS  (192*1024)                    // 16*8192 int
#define WS_XBF    (1ull<<20)                    // x_bf 32MB swizzled (w2_bf aliases after fc1)
#define WS_W2BF   WS_XBF
#define WS_H      (WS_XBF + 33554432ull)        // h: 36864*512*2 = 36MB
#define WS_W1BF   (WS_H + 37748736ull)          // w1_bf 32MB (dead after fc1)
#define WS_YP     WS_W1BF                       // yp: 36864*2048*2 = 144MB, overlays w1_bf

static __device__ __forceinline__ unsigned short f2bf(float f) {
    __hip_bfloat16 h = __float2bfloat16(f);
    return *reinterpret_cast<unsigned short*>(&h);
}

static __device__ __forceinline__ void gload16(const unsigned short* g, unsigned short* lds) {
    __builtin_amdgcn_global_load_lds(
        (const __attribute__((address_space(1))) unsigned int*)g,
        (__attribute__((address_space(3))) unsigned int*)lds, 16, 0, 0);
}

#define MFMA16(ai, bi) \
    acc[0][0] = __builtin_amdgcn_mfma_f32_16x16x32_bf16(ai##0, bi##0, acc[0][0], 0, 0, 0); \
    acc[0][1] = __builtin_amdgcn_mfma_f32_16x16x32_bf16(ai##0, bi##1, acc[0][1], 0, 0, 0); \
    acc[0][2] = __builtin_amdgcn_mfma_f32_16x16x32_bf16(ai##0, bi##2, acc[0][2], 0, 0, 0); \
    acc[0][3] = __builtin_amdgcn_mfma_f32_16x16x32_bf16(ai##0, bi##3, acc[0][3], 0, 0, 0); \
    acc[1][0] = __builtin_amdgcn_mfma_f32_16x16x32_bf16(ai##1, bi##0, acc[1][0], 0, 0, 0); \
    acc[1][1] = __builtin_amdgcn_mfma_f32_16x16x32_bf16(ai##1, bi##1, acc[1][1], 0, 0, 0); \
    acc[1][2] = __builtin_amdgcn_mfma_f32_16x16x32_bf16(ai##1, bi##2, acc[1][2], 0, 0, 0); \
    acc[1][3] = __builtin_amdgcn_mfma_f32_16x16x32_bf16(ai##1, bi##3, acc[1][3], 0, 0, 0); \
    acc[2][0] = __builtin_amdgcn_mfma_f32_16x16x32_bf16(ai##2, bi##0, acc[2][0], 0, 0, 0); \
    acc[2][1] = __builtin_amdgcn_mfma_f32_16x16x32_bf16(ai##2, bi##1, acc[2][1], 0, 0, 0); \
    acc[2][2] = __builtin_amdgcn_mfma_f32_16x16x32_bf16(ai##2, bi##2, acc[2][2], 0, 0, 0); \
    acc[2][3] = __builtin_amdgcn_mfma_f32_16x16x32_bf16(ai##2, bi##3, acc[2][3], 0, 0, 0); \
    acc[3][0] = __builtin_amdgcn_mfma_f32_16x16x32_bf16(ai##3, bi##0, acc[3][0], 0, 0, 0); \
    acc[3][1] = __builtin_amdgcn_mfma_f32_16x16x32_bf16(ai##3, bi##1, acc[3][1], 0, 0, 0); \
    acc[3][2] = __builtin_amdgcn_mfma_f32_16x16x32_bf16(ai##3, bi##2, acc[3][2], 0, 0, 0); \
    acc[3][3] = __builtin_amdgcn_mfma_f32_16x16x32_bf16(ai##3, bi##3, acc[3][3], 0, 0, 0);

#define PHASE_TAIL \
    __builtin_amdgcn_s_barrier(); \
    asm volatile("s_waitcnt lgkmcnt(0)" ::: "memory"); \
    __builtin_amdgcn_sched_barrier(0); \
    __builtin_amdgcn_s_setprio(1); \
    MFMA16(a, b) \
    __builtin_amdgcn_s_setprio(0); \
    __builtin_amdgcn_sched_barrier(0); \
    __builtin_amdgcn_s_barrier();

// ---------------- router: LDS-staged x row, fp64 logits, top-4; emits x_bf (swizzled, R12 layout) ----------------
__global__ __launch_bounds__(256) void router_kernel(
    const float* __restrict__ x, const float* __restrict__ Wr,
    const float* __restrict__ br, unsigned short* __restrict__ sel,
    unsigned short* __restrict__ x_bf)
{
    __shared__ float xs[4][IN_F];
    const int tid = threadIdx.x;
    const int lt = tid & 63;
    const int wv = tid >> 6;
    const int tok = blockIdx.x * 4 + wv;
    float4* xl = (float4*)xs[wv];
    const float4* xp = (const float4*)(x + (size_t)tok * IN_F);
    #pragma unroll
    for (int i = 0; i < 8; ++i) xl[lt + i * 64] = xp[lt + i * 64];
    __syncthreads();
    const int e = lt >> 2, p = lt & 3;
    const float4* wp = (const float4*)(Wr + (size_t)e * IN_F);
    double s = 0.0;
    for (int j = p; j < IN_F / 4; j += 4) {
        float4 a = xl[j], w = wp[j];
        s += (double)a.x * w.x + (double)a.y * w.y + (double)a.z * w.z + (double)a.w * w.w;
    }
    s += __shfl_down(s, 2);
    s += __shfl_down(s, 1);
    __shared__ double logits[4][NB];
    if (p == 0) logits[wv][e] = s + (double)br[e];
    __syncthreads();
    if (lt == 0) {
        unsigned used = 0, packed = 0;
        #pragma unroll
        for (int kk = 0; kk < 4; ++kk) {
            int best = 0; double bv = -1.0e300;
            #pragma unroll
            for (int i = 0; i < NB; ++i)
                if (!((used >> i) & 1u) && logits[wv][i] > bv) { bv = logits[wv][i]; best = i; }
            used |= 1u << best;
            packed |= (unsigned)best << (4 * kk);
        }
        sel[tok] = (unsigned short)packed;
    }
    // emit bf16 row in the swizzled layout R12's fc1 expects:
    // x_bf[tok][slot ^ (tok&7)] = bf16(x[tok][slot])  (slot = 16B group of 8 elems)
    const int t7 = tok & 7;
    unsigned short* drow = x_bf + (size_t)tok * IN_F;
    #pragma unroll
    for (int i = 0; i < 4; ++i) {
        const int slot = lt + i * 64;
        const float* sp = &xs[wv][slot * 8];
        ushort8 o;
        #pragma unroll
        for (int j = 0; j < 8; ++j) o[j] = f2bf(sp[j]);
        *(ushort8*)(drow + ((slot ^ t7) << 3)) = o;
    }
}

// ---------------- build per-expert token lists + inverse map (deterministic) ----------------
__global__ __launch_bounds__(256) void build_lists_kernel(
    const unsigned short* __restrict__ sel, int* __restrict__ counts,
    int* __restrict__ lists, unsigned* __restrict__ inv)
{
    const int e = blockIdx.x;
    const int t = threadIdx.x;
    unsigned short mysel[N_TOK / 256];
    int cnt = 0;
    #pragma unroll
    for (int i = 0; i < N_TOK / 256; ++i) {
        unsigned s = sel[i * 256 + t];
        mysel[i] = (unsigned short)s;
        bool m = ((s & 15u) == (unsigned)e) | (((s >> 4) & 15u) == (unsigned)e) |
                 (((s >> 8) & 15u) == (unsigned)e) | (((s >> 12) & 15u) == (unsigned)e);
        cnt += m ? 1 : 0;
    }
    __shared__ int ps[256];
    ps[t] = cnt;
    __syncthreads();
    #pragma unroll
    for (int off = 1; off < 256; off <<= 1) {
        int v = (t >= off) ? ps[t - off] : 0;
        __syncthreads();
        ps[t] += v;
        __syncthreads();
    }
    int pos = ps[t] - cnt;
    if (t == 255) counts[e] = ps[255];
    #pragma unroll
    for (int i = 0; i < N_TOK / 256; ++i) {
        unsigned s = mysel[i];
        bool m = ((s & 15u) == (unsigned)e) | (((s >> 4) & 15u) == (unsigned)e) |
                 (((s >> 8) & 15u) == (unsigned)e) | (((s >> 12) & 15u) == (unsigned)e);
        if (m) {
            const int tok = i * 256 + t;
            int j = ((s & 15u) == (unsigned)e) ? 0 :
                    (((s >> 4) & 15u) == (unsigned)e) ? 1 :
                    (((s >> 8) & 15u) == (unsigned)e) ? 2 : 3;
            inv[tok * 4 + j] = ((unsigned)e << 16) | (unsigned)pos;
            lists[e * N_TOK + pos++] = tok;
        }
    }
}

__global__ void scan_kernel(const int* __restrict__ counts, int* __restrict__ tstart)
{
    if (threadIdx.x == 0) {
        int acc = 0;
        for (int i = 0; i < NB; ++i) { tstart[i] = acc; acc += (counts[i] + BM2 - 1) / BM2; }
        tstart[NB] = acc;
    }
}

// ---------------- W convert: fp32 -> bf16 with per-row XOR-swizzle of 16B k-slots ----------------
__global__ __launch_bounds__(256) void convert_swz_kernel(
    const float* __restrict__ src, unsigned short* __restrict__ dst, int sh)
{
    const int total = 1 << 21;
    for (int id = blockIdx.x * 256 + threadIdx.x; id < total; id += 2048 * 256) {
        const int row = id >> sh;
        const int sr  = id & ((1 << sh) - 1);
        const int ps  = sr ^ (row & 7);
        const float4* s4 = (const float4*)(src + ((size_t)id << 3));
        float4 p0 = s4[0], p1 = s4[1];
        ushort8 o;
        o[0] = f2bf(p0.x); o[1] = f2bf(p0.y); o[2] = f2bf(p0.z); o[3] = f2bf(p0.w);
        o[4] = f2bf(p1.x); o[5] = f2bf(p1.y); o[6] = f2bf(p1.z); o[7] = f2bf(p1.w);
        *(ushort8*)(dst + (((size_t)(row) << sh) << 3) + ((size_t)ps << 3)) = o;
    }
}

// ======== fc1: 256x128 tile, 8 waves, triple-buffered phase-interleaved K-loop (R12-green) ========
__global__ __launch_bounds__(512) void fc1_kernel(
    const unsigned short* __restrict__ x_bf, const unsigned short* __restrict__ w1_bf,
    const int* __restrict__ lists, const int* __restrict__ counts,
    const int* __restrict__ tstart, unsigned short* __restrict__ h)
{
    __shared__ unsigned short lds[73728];   // 3 x (A 32KB + B 16KB) = 144KB
    const int bid = blockIdx.x;
    const int newid = (bid & 7) * 72 + (bid >> 3);   // bijective: 576 = 8*72
    const int nt = newid & 3, mt = newid >> 2;
    if (mt >= tstart[NB]) return;
    int b = 0;
    #pragma unroll
    for (int i = 1; i < NB; ++i) b += (mt >= tstart[i]);
    const int cnt  = counts[b];
    const int row0 = (mt - tstart[b]) * BM2;
    const int tid  = threadIdx.x;
    const int wave = tid >> 6, lane = tid & 63;
    const int sph = lane & 7;
    const int rbase = wave * 8 + (lane >> 3);        // 0..63

    const unsigned short* aS[4];
    const unsigned short* bS[2];
    #pragma unroll
    for (int i = 0; i < 4; ++i) {
        const int r = i * 64 + rbase;
        const int gr = min(row0 + r, cnt - 1);
        const int tok = lists[b * N_TOK + gr];
        aS[i] = x_bf + (size_t)tok * IN_F + ((sph ^ (r & 7) ^ (tok & 7)) << 3);
    }
    #pragma unroll
    for (int j = 0; j < 2; ++j) {
        const int r = j * 64 + rbase;
        bS[j] = w1_bf + (size_t)(b * BS + nt * 128 + r) * IN_F + (sph << 3);
    }
    const int wbase = wave * 512;

    const int lr16 = lane & 15, q = lane >> 4;
    const int wm = (wave >> 1) * 64, wn = (wave & 1) * 64;
    int offA[4], offB[4];
    #pragma unroll
    for (int i = 0; i < 4; ++i) { const int r = wm + i * 16 + lr16; offA[i] = r * 64 + ((q ^ (r & 7)) << 3); }
    #pragma unroll
    for (int j = 0; j < 4; ++j) { const int r = wn + j * 16 + lr16; offB[j] = r * 64 + ((q ^ (r & 7)) << 3); }

    f32x4 acc[4][4];
    #pragma unroll
    for (int i = 0; i < 4; ++i)
        #pragma unroll
        for (int j = 0; j < 4; ++j) acc[i][j] = (f32x4)0.0f;

#define STA1(k, buf, i) gload16(aS[i] + (size_t)(k) * 64, lds + (buf) * 24576 + (i) * 4096 + wbase)
#define STB1(k, buf, j) gload16(bS[j] + (size_t)(k) * 64, lds + (buf) * 24576 + 16384 + (j) * 4096 + wbase)

    STA1(0,0,0); STA1(0,0,1); STA1(0,0,2); STA1(0,0,3); STB1(0,0,0); STB1(0,0,1);
    STA1(1,1,0); STA1(1,1,1); STA1(1,1,2); STA1(1,1,3); STB1(1,1,0); STB1(1,1,1);
    asm volatile("s_waitcnt vmcnt(6)" ::: "memory");
    __builtin_amdgcn_s_barrier();

    const int NK = IN_F / 64;   // 32
    int cur = 0;
    for (int k = 0; k < NK; ++k) {
        const unsigned short* Ab = lds + cur * 24576;
        const unsigned short* Bb = Ab + 16384;
        const int nxt = (cur == 0) ? 2 : cur - 1;    // (cur+2)%3
        bf16x8 a0 = *(const bf16x8*)&Ab[offA[0]];
        bf16x8 a1 = *(const bf16x8*)&Ab[offA[1]];
        bf16x8 a2 = *(const bf16x8*)&Ab[offA[2]];
        bf16x8 a3 = *(const bf16x8*)&Ab[offA[3]];
        bf16x8 b0 = *(const bf16x8*)&Bb[offB[0]];
        bf16x8 b1 = *(const bf16x8*)&Bb[offB[1]];
        bf16x8 b2 = *(const bf16x8*)&Bb[offB[2]];
        bf16x8 b3 = *(const bf16x8*)&Bb[offB[3]];
        if (k + 2 < NK) { STA1(k + 2, nxt, 0); STA1(k + 2, nxt, 1); STB1(k + 2, nxt, 0); }
        PHASE_TAIL
        a0 = *(const bf16x8*)&Ab[offA[0] ^ 32];
        a1 = *(const bf16x8*)&Ab[offA[1] ^ 32];
        a2 = *(const bf16x8*)&Ab[offA[2] ^ 32];
        a3 = *(const bf16x8*)&Ab[offA[3] ^ 32];
        b0 = *(const bf16x8*)&Bb[offB[0] ^ 32];
        b1 = *(const bf16x8*)&Bb[offB[1] ^ 32];
        b2 = *(const bf16x8*)&Bb[offB[2] ^ 32];
        b3 = *(const bf16x8*)&Bb[offB[3] ^ 32];
        if (k + 2 < NK) {
            STA1(k + 2, nxt, 2); STA1(k + 2, nxt, 3); STB1(k + 2, nxt, 1);
            asm volatile("s_waitcnt vmcnt(6)" ::: "memory");
        } else if (k + 1 < NK) {
            asm volatile("s_waitcnt vmcnt(0)" ::: "memory");
        }
        PHASE_TAIL
        cur = (cur == 2) ? 0 : cur + 1;
    }
    // epilogue: exact gelu, store h pre-swizzled by row&7 (16B-slot XOR)
    #pragma unroll
    for (int i = 0; i < 4; ++i) {
        #pragma unroll
        for (int r = 0; r < 4; ++r) {
            const int lrow = wm + i * 16 + q * 4 + r;
            if (row0 + lrow < cnt) {
                const size_t hrow = (size_t)(mt * BM2 + lrow) * BS;
                const int r7 = (lrow & 7) << 3;
                #pragma unroll
                for (int j = 0; j < 4; ++j) {
                    const int col = nt * 128 + wn + j * 16 + lr16;
                    float v = acc[i][j][r];
                    v = 0.5f * v * (1.0f + erff(v * 0.70710678118654752f));
                    h[hrow + (col ^ r7)] = f2bf(v);
                }
            }
        }
    }
#undef STA1
#undef STB1
}

// ======== fc2: 256x256 tile, 8 waves (2x4), 2-buffer phase-interleaved; h @ W2_b^T -> yp fp16 (R12-green) ========
__global__ __launch_bounds__(512) void fc2_kernel(
    const unsigned short* __restrict__ h, const unsigned short* __restrict__ w2_bf,
    const int* __restrict__ counts, const int* __restrict__ tstart,
    _Float16* __restrict__ yp)
{
    __shared__ unsigned short lds[2][32768];   // per buf: A 32KB + B 32KB
    const int bid = blockIdx.x;
    const int newid = (bid & 7) * 144 + (bid >> 3);  // bijective: 1152 = 8*144
    const int nt = newid & 7, mt = newid >> 3;
    if (mt >= tstart[NB]) return;
    int b = 0;
    #pragma unroll
    for (int i = 1; i < NB; ++i) b += (mt >= tstart[i]);
    const int cnt  = counts[b];
    const int row0 = (mt - tstart[b]) * BM2;
    const int tid  = threadIdx.x;
    const int wave = tid >> 6, lane = tid & 63;
    const int sph = lane & 7;
    const int rbase = wave * 8 + (lane >> 3);        // 0..63

    const unsigned short* aS[4];
    const unsigned short* bS[4];
    #pragma unroll
    for (int g = 0; g < 4; ++g) {
        const int r = g * 64 + rbase;
        aS[g] = h + (size_t)(mt * BM2 + r) * BS + (sph << 3);
        bS[g] = w2_bf + (size_t)(nt * 256 + r) * OUT_F + b * BS + (sph << 3);
    }
    const int wbase = wave * 512;

    const int lr16 = lane & 15, q = lane >> 4;
    const int wr = (wave >> 2) * 128, wc = (wave & 3) * 64;
    int offA[8], offB[4];
    #pragma unroll
    for (int i = 0; i < 8; ++i) { const int r = wr + i * 16 + lr16; offA[i] = r * 64 + ((q ^ (r & 7)) << 3); }
    #pragma unroll
    for (int j = 0; j < 4; ++j) { const int r = wc + j * 16 + lr16; offB[j] = 16384 + r * 64 + ((q ^ (r & 7)) << 3); }

    f32x4 acc[8][4];
    #pragma unroll
    for (int i = 0; i < 8; ++i)
        #pragma unroll
        for (int j = 0; j < 4; ++j) acc[i][j] = (f32x4)0.0f;

#define ST2(k, buf) \
    { _Pragma("unroll") for (int g = 0; g < 4; ++g) \
        gload16(aS[g] + (size_t)(k) * 64, &lds[buf][g * 4096 + wbase]); \
      _Pragma("unroll") for (int g = 0; g < 4; ++g) \
        gload16(bS[g] + (size_t)(k) * 64, &lds[buf][16384 + g * 4096 + wbase]); }

#define MFMA_8x4 \
    __builtin_amdgcn_s_barrier(); \
    asm volatile("s_waitcnt lgkmcnt(0)" ::: "memory"); \
    __builtin_amdgcn_sched_barrier(0); \
    __builtin_amdgcn_s_setprio(1); \
    _Pragma("unroll") for (int i = 0; i < 8; ++i) \
        _Pragma("unroll") for (int j = 0; j < 4; ++j) \
            acc[i][j] = __builtin_amdgcn_mfma_f32_16x16x32_bf16(a[i], bb[j], acc[i][j], 0, 0, 0); \
    __builtin_amdgcn_s_setprio(0); \
    __builtin_amdgcn_sched_barrier(0); \
    __builtin_amdgcn_s_barrier();

    ST2(0, 0);
    asm volatile("s_waitcnt vmcnt(0)" ::: "memory");
    __builtin_amdgcn_s_barrier();

    const int NK = BS / 64;   // 8
    for (int k = 0; k < NK; ++k) {
        const int cur = k & 1;
        const unsigned short* L = lds[cur];
        // phase A: ds_read half0, issue ALL of tile k+1's staging
        {
            bf16x8 a[8], bb[4];
            #pragma unroll
            for (int i = 0; i < 8; ++i) a[i]  = *(const bf16x8*)&L[offA[i]];
            #pragma unroll
            for (int j = 0; j < 4; ++j) bb[j] = *(const bf16x8*)&L[offB[j]];
            if (k + 1 < NK) ST2(k + 1, cur ^ 1);
            MFMA_8x4
        }
        // phase B: ds_read half1; drain staging BEFORE the barrier (race-safe)
        {
            bf16x8 a[8], bb[4];
            #pragma unroll
            for (int i = 0; i < 8; ++i) a[i]  = *(const bf16x8*)&L[offA[i] ^ 32];
            #pragma unroll
            for (int j = 0; j < 4; ++j) bb[j] = *(const bf16x8*)&L[offB[j] ^ 32];
            if (k + 1 < NK) asm volatile("s_waitcnt vmcnt(0)" ::: "memory");
            MFMA_8x4
        }
    }
    // epilogue: store fp16 partials
    #pragma unroll
    for (int i = 0; i < 8; ++i) {
        #pragma unroll
        for (int r = 0; r < 4; ++r) {
            const int lrow = wr + i * 16 + q * 4 + r;
            if (row0 + lrow < cnt) {
                _Float16* yrow = yp + (size_t)(mt * BM2 + lrow) * IN_F + nt * 256 + wc + lr16;
                #pragma unroll
                for (int j = 0; j < 4; ++j)
                    yrow[j * 16] = (_Float16)acc[i][j][r];
            }
        }
    }
#undef ST2
#undef MFMA_8x4
}

// ---------------- reduce: y[t] = sum of the token's 4 fp16 partial rows ----------------
__global__ __launch_bounds__(256) void reduce_kernel(
    const _Float16* __restrict__ yp, const unsigned* __restrict__ inv,
    const int* __restrict__ tstart, float* __restrict__ y)
{
    const int tok = blockIdx.x;
    __shared__ size_t rbase[4];
    if (threadIdx.x < 4) {
        unsigned v = inv[tok * 4 + threadIdx.x];
        rbase[threadIdx.x] = (size_t)(tstart[v >> 16] * BM2 + (int)(v & 0xFFFFu)) * IN_F;
    }
    __syncthreads();
    const int c = threadIdx.x * 8;
    f16x8 v0 = *(const f16x8*)(yp + rbase[0] + c);
    f16x8 v1 = *(const f16x8*)(yp + rbase[1] + c);
    f16x8 v2 = *(const f16x8*)(yp + rbase[2] + c);
    f16x8 v3 = *(const f16x8*)(yp + rbase[3] + c);
    float out[8];
    #pragma unroll
    for (int j = 0; j < 8; ++j)
        out[j] = (float)v0[j] + (float)v1[j] + (float)v2[j] + (float)v3[j];
    float4* yo = (float4*)(y + (size_t)tok * IN_F + c);
    yo[0] = make_float4(out[0], out[1], out[2], out[3]);
    yo[1] = make_float4(out[4], out[5], out[6], out[7]);
}

extern "C" void kernel_launch(void* const* d_in, const int* in_sizes, int n_in,
                              void* d_out, int out_size, void* d_ws, size_t ws_size,
                              hipStream_t stream) {
    const float* x  = (const float*)d_in[0];
    const float* Wr = (const float*)d_in[1];
    const float* br = (const float*)d_in[2];
    const float* W1 = (const float*)d_in[3];
    const float* W2 = (const float*)d_in[4];
    float* y = (float*)d_out;
    char* ws = (char*)d_ws;
    int* counts = (int*)(ws + WS_COUNTS);
    int* tstart = (int*)(ws + WS_TSTART);
    unsigned short* sel = (unsigned short*)(ws + WS_SEL);
    unsigned* inv = (unsigned*)(ws + WS_INV);
    int* lists  = (int*)(ws + WS_LISTS);
    unsigned short* x_bf  = (unsigned short*)(ws + WS_XBF);
    unsigned short* w1_bf = (unsigned short*)(ws + WS_W1BF);
    unsigned short* w2_bf = (unsigned short*)(ws + WS_W2BF);
    unsigned short* h     = (unsigned short*)(ws + WS_H);
    _Float16* yp          = (_Float16*)(ws + WS_YP);

    hipLaunchKernelGGL(router_kernel, dim3(N_TOK / 4), dim3(256), 0, stream, x, Wr, br, sel, x_bf);
    hipLaunchKernelGGL(build_lists_kernel, dim3(NB), dim3(256), 0, stream, sel, counts, lists, inv);
    hipLaunchKernelGGL(scan_kernel, dim3(1), dim3(64), 0, stream, counts, tstart);
    hipLaunchKernelGGL(convert_swz_kernel, dim3(2048), dim3(256), 0, stream, W1, w1_bf, 8);
    hipLaunchKernelGGL(fc1_kernel, dim3(4 * MAX_MT2), dim3(512), 0, stream, x_bf, w1_bf, lists, counts, tstart, h);
    hipLaunchKernelGGL(convert_swz_kernel, dim3(2048), dim3(256), 0, stream, W2, w2_bf, 10);
    hipLaunchKernelGGL(fc2_kernel, dim3(8 * MAX_MT2), dim3(512), 0, stream, h, w2_bf, counts, tstart, yp);
    hipLaunchKernelGGL(reduce_kernel, dim3(N_TOK), dim3(256), 0, stream, yp, inv, tstart, y);
}